// Round 7
// baseline (149.938 us; speedup 1.0000x reference)
//
#include <hip/hip_runtime.h>
#include <hip/hip_bf16.h>

// ScaledDotProductAttention: B=2,H=16,D=64,N=2048, fp32 in/out.
// Layout per head: Q,K,V are D x N (N contiguous). scores = Q^T K / sqrt(N),
// P = softmax_k, out[q][v] = sum_k P[q][k] V[v][k], out is N x D.
// Max-free softmax (|scores| <~ 1.5, exp-safe) -> split-K partials just ADD.
// Round 10: split-K ACROSS BLOCKS. 1024 blocks (256 thr, 4 waves x 32 q,
// 1024 keys each) -> 4 blocks/CU = 16 waves/CU (4/SIMD) at R8's proven LDS
// economics (32-q amortization, ~35% LDS pipe) and 256-thr staging (no R7
// register thrash). Partial O (unnormalized) + l go to workspace; a tiny
// combine kernel does Out=(O0+O1)/(l0+l1). Falls back to single-kernel R8
// path if ws_size < 34.1 MB. Dataflow (in-reg P pl32+pl16, ones-MFMA l)
// HW-verified R5/R7/R8.

typedef __attribute__((ext_vector_type(8))) short short8;   // 8 bf16 (A/B frag)
typedef __attribute__((ext_vector_type(4))) float f32x4;    // 16x16 C/D frag

#define NN 2048
#define DD 64
#define ROWB 144   // LDS row: 64 bf16 (128 B) + 16 B pad
#define NBH 32     // B*H

#if __has_builtin(__builtin_amdgcn_exp2f)
#define EXP2(x) __builtin_amdgcn_exp2f(x)
#else
#define EXP2(x) __expf(0.69314718056f * (x))
#endif

__device__ __forceinline__ unsigned pk2(float a, float b) {
  __hip_bfloat162 hh = __float22bfloat162_rn(make_float2(a, b));  // a -> low short
  unsigned u; __builtin_memcpy(&u, &hh, 4); return u;
}
__device__ __forceinline__ short f2bf(float f) {
  union { float f; unsigned u; } x; x.f = f;
  unsigned r = (x.u + 0x7fffu + ((x.u >> 16) & 1u)) >> 16;  // RNE
  return (short)r;
}
// x[32:63] <-> y[0:31]
__device__ __forceinline__ void pl32swap(unsigned &x, unsigned &y) {
  asm("v_permlane32_swap_b32 %0, %1" : "+v"(x), "+v"(y));
}
// x[16:31]<->y[0:15], x[48:63]<->y[32:47]
__device__ __forceinline__ void pl16swap(unsigned &x, unsigned &y) {
  asm("v_permlane16_swap_b32 %0, %1" : "+v"(x), "+v"(y));
}

template <int SPLIT>
__global__ __launch_bounds__(256, 4) void attn_kernel(
    const float* __restrict__ Q, const float* __restrict__ K,
    const float* __restrict__ V, float* __restrict__ Out,
    float* __restrict__ Opart, float* __restrict__ Lpart) {
  const int tid  = threadIdx.x;
  const int wave = tid >> 6, lane = tid & 63;
  const int quad = lane >> 4, l16 = lane & 15;

  int bh, qblk, kh;
  if (SPLIT) {            // 1024 blocks: (bh, qblk, key-half)
    bh = blockIdx.x >> 5; qblk = (blockIdx.x >> 1) & 15; kh = blockIdx.x & 1;
  } else {                // 512 blocks: (bh, qblk)
    bh = blockIdx.x >> 4; qblk = blockIdx.x & 15; kh = 0;
  }
  const int kb    = SPLIT ? kh * 1024 : 0;   // first key of this block's range
  const int ITERS = SPLIT ? 16 : 32;         // 64-key chunks in range

  const float* Qh = Q + (size_t)bh * DD * NN;
  const float* Kh = K + (size_t)bh * DD * NN;
  const float* Vh = V + (size_t)bh * DD * NN;

  __shared__ __align__(16) char ldsK[2][64 * ROWB];   // KT: [key][d], xor-swizzled 16B groups
  __shared__ __align__(16) char ldsV[2][64 * ROWB];   // V:  [v][key], linear

  // ---- Q as B-fragments (16x16x32): B[k=quad*8+j][n=l16]; 2 q-tiles/wave ----
  const float qscale = 0.031881407f;  // log2(e)/sqrt(2048)
  const int qb = qblk * 128 + wave * 32;
  short8 bQ[2][2];
#pragma unroll
  for (int qt = 0; qt < 2; ++qt)
#pragma unroll
    for (int hh = 0; hh < 2; ++hh)
#pragma unroll
      for (int j = 0; j < 8; ++j) {
        int d = hh * 32 + quad * 8 + j;
        bQ[qt][hh][j] = f2bf(Qh[(size_t)d * NN + qb + qt * 16 + l16] * qscale);
      }

  // ones B-fragment for l row-sum on the MFMA pipe
  short8 onesB;
#pragma unroll
  for (int j = 0; j < 8; ++j) onesB[j] = (short)0x3F80;  // bf16 1.0

  f32x4 accO[2][4];   // [qt][vt]: row q=quad*4+r, col v=vt*16+l16
  f32x4 accL[2];      // [qt]: reg r holds l[q=qb+qt*16+quad*4+r] (all cols equal)
#pragma unroll
  for (int qt = 0; qt < 2; ++qt) {
    accL[qt] = (f32x4){0.f, 0.f, 0.f, 0.f};
#pragma unroll
    for (int vt = 0; vt < 4; ++vt) accO[qt][vt] = (f32x4){0.f, 0.f, 0.f, 0.f};
  }

  // ---- staging: 256 threads stage 64 keys of K and V per chunk ----
  const int ka = tid & 31, kg = tid >> 5;        // K: d-pair (2ka,2ka+1), keys kg*8..+7
  const int vv = tid >> 2, vko = (tid & 3) * 16; // V: row vv, 16 keys
  const float* kbase0 = Kh + (size_t)(2 * ka) * NN + kb + kg * 8;
  const float* kbase1 = kbase0 + NN;
  const float* vbase  = Vh + (size_t)vv * NN + kb + vko;

  float kA[8], kB[8], vA[16];
  auto load_kv = [&](int k0) {
    const float4* p0 = (const float4*)(kbase0 + k0);
    const float4* p1 = (const float4*)(kbase1 + k0);
    float4 a0 = p0[0], a1 = p0[1];
    float4 b0 = p1[0], b1 = p1[1];
    kA[0] = a0.x; kA[1] = a0.y; kA[2] = a0.z; kA[3] = a0.w;
    kA[4] = a1.x; kA[5] = a1.y; kA[6] = a1.z; kA[7] = a1.w;
    kB[0] = b0.x; kB[1] = b0.y; kB[2] = b0.z; kB[3] = b0.w;
    kB[4] = b1.x; kB[5] = b1.y; kB[6] = b1.z; kB[7] = b1.w;
    const float4* pv = (const float4*)(vbase + k0);
    float4 c0 = pv[0], c1 = pv[1], c2 = pv[2], c3 = pv[3];
    vA[0]  = c0.x; vA[1]  = c0.y; vA[2]  = c0.z; vA[3]  = c0.w;
    vA[4]  = c1.x; vA[5]  = c1.y; vA[6]  = c1.z; vA[7]  = c1.w;
    vA[8]  = c2.x; vA[9]  = c2.y; vA[10] = c2.z; vA[11] = c2.w;
    vA[12] = c3.x; vA[13] = c3.y; vA[14] = c3.z; vA[15] = c3.w;
  };
  auto store_kv = [&](char* bK, char* bV) {
#pragma unroll
    for (int j = 0; j < 8; ++j) {
      int k = kg * 8 + j;
      int g = (ka >> 2) ^ ((k >> 1) & 7);
      *(unsigned*)&bK[k * ROWB + g * 16 + (ka & 3) * 4] = pk2(kA[j], kB[j]);
    }
    uint4 w0 = make_uint4(pk2(vA[0], vA[1]),  pk2(vA[2], vA[3]),
                          pk2(vA[4], vA[5]),  pk2(vA[6], vA[7]));
    uint4 w1 = make_uint4(pk2(vA[8], vA[9]),  pk2(vA[10], vA[11]),
                          pk2(vA[12], vA[13]), pk2(vA[14], vA[15]));
    *(uint4*)&bV[vv * ROWB + vko * 2]      = w0;
    *(uint4*)&bV[vv * ROWB + vko * 2 + 16] = w1;
  };

  // ---- prologue: stage chunk 0 ----
  load_kv(0);
  store_kv(ldsK[0], ldsV[0]);
  __syncthreads();

  const int swr = l16 >> 1;   // KT read-side xor swizzle

  for (int it = 0; it < ITERS; ++it) {
    const int cur = it & 1;
    // prefetch next chunk into registers (wrapped on last iter; result unused)
    load_kv(((it + 1) & (ITERS - 1)) * 64);

    const char* cK = ldsK[cur];
    const char* cV = ldsV[cur];

#pragma unroll
    for (int ks = 0; ks < 2; ++ks) {        // 32-key step
      unsigned u[2][2][2];                  // [qt][kt&1][slot]
#pragma unroll
      for (int k2 = 0; k2 < 2; ++k2) {
        const int kt = ks * 2 + k2;
        const char* row = &cK[(kt * 16 + l16) * ROWB];
        short8 aK0 = *(const short8*)&row[(quad ^ swr) * 16];
        short8 aK1 = *(const short8*)&row[((4 + quad) ^ swr) * 16];
#pragma unroll
        for (int qt = 0; qt < 2; ++qt) {
          f32x4 z = (f32x4){0.f, 0.f, 0.f, 0.f};
          f32x4 sT = __builtin_amdgcn_mfma_f32_16x16x32_bf16(aK0, bQ[qt][0], z, 0, 0, 0);
          sT = __builtin_amdgcn_mfma_f32_16x16x32_bf16(aK1, bQ[qt][1], sT, 0, 0, 0);
          float p0 = EXP2(sT[0]), p1 = EXP2(sT[1]);
          float p2 = EXP2(sT[2]), p3 = EXP2(sT[3]);
          u[qt][k2][0] = pk2(p0, p1);
          u[qt][k2][1] = pk2(p2, p3);
        }
      }
      // A-frag assembly (HW-verified): target (quad g, u32 c) <-
      // u[kt&1 = g>>1][c&1] of quad 2*(g&1)+(c>>1); pl32+pl16 -> (c, c+2).
      short8 aP[2];
#pragma unroll
      for (int qt = 0; qt < 2; ++qt) {
        unsigned c0 = u[qt][0][0], c2 = u[qt][1][0];
        pl32swap(c0, c2); pl16swap(c0, c2);
        unsigned c1 = u[qt][0][1], c3 = u[qt][1][1];
        pl32swap(c1, c3); pl16swap(c1, c3);
        unsigned w[4] = {c0, c1, c2, c3};
        __builtin_memcpy(&aP[qt], w, 16);
        // l[q] += sum_k P[q][k] on the MFMA pipe (B = ones)
        accL[qt] = __builtin_amdgcn_mfma_f32_16x16x32_bf16(aP[qt], onesB, accL[qt], 0, 0, 0);
      }
#pragma unroll
      for (int vt = 0; vt < 4; ++vt) {
        short8 bVf = *(const short8*)&cV[(vt * 16 + l16) * ROWB + ks * 64 + quad * 16];
        accO[0][vt] = __builtin_amdgcn_mfma_f32_16x16x32_bf16(aP[0], bVf, accO[0][vt], 0, 0, 0);
        accO[1][vt] = __builtin_amdgcn_mfma_f32_16x16x32_bf16(aP[1], bVf, accO[1][vt], 0, 0, 0);
      }
    }

    // ---- write prefetched chunk into the other buffer, single barrier ----
    store_kv(ldsK[cur ^ 1], ldsV[cur ^ 1]);
    __syncthreads();
  }

  if (SPLIT) {
    // ---- write unnormalized partial O and partial l to workspace ----
    float* Op = Opart + (size_t)kh * ((size_t)NBH * NN * DD) + (size_t)bh * NN * DD;
    float* Lp = Lpart + kh * (NBH * NN) + bh * NN;
#pragma unroll
    for (int qt = 0; qt < 2; ++qt)
#pragma unroll
      for (int r = 0; r < 4; ++r) {
        const int q = qb + qt * 16 + quad * 4 + r;
#pragma unroll
        for (int vt = 0; vt < 4; ++vt)
          Op[(size_t)q * DD + vt * 16 + l16] = accO[qt][vt][r];
        if (l16 == 0) Lp[q] = accL[qt][r];
      }
  } else {
    // ---- single-kernel path: l is lane-local in accL; normalize, store ----
    float* Oh = Out + (size_t)bh * NN * DD;
#pragma unroll
    for (int qt = 0; qt < 2; ++qt)
#pragma unroll
      for (int r = 0; r < 4; ++r) {
        const float inv = 1.0f / accL[qt][r];
        const int q = qb + qt * 16 + quad * 4 + r;
#pragma unroll
        for (int vt = 0; vt < 4; ++vt)
          Oh[(size_t)q * DD + vt * 16 + l16] = accO[qt][vt][r] * inv;
      }
  }
}

// Out = (O0 + O1) / (l0 + l1); 8 floats per thread, fully coalesced.
__global__ __launch_bounds__(256, 8) void combine_kernel(
    const float* __restrict__ O0, const float* __restrict__ O1,
    const float* __restrict__ L0, const float* __restrict__ L1,
    float* __restrict__ Out) {
  const size_t e  = ((size_t)blockIdx.x * 256 + threadIdx.x) * 8;
  const size_t qi = e >> 6;   // global q-row index (bh*NN + q)
  const float linv = 1.0f / (L0[qi] + L1[qi]);
  float4 a0 = *(const float4*)(O0 + e), a1 = *(const float4*)(O0 + e + 4);
  float4 b0 = *(const float4*)(O1 + e), b1 = *(const float4*)(O1 + e + 4);
  float4 r0, r1;
  r0.x = (a0.x + b0.x) * linv; r0.y = (a0.y + b0.y) * linv;
  r0.z = (a0.z + b0.z) * linv; r0.w = (a0.w + b0.w) * linv;
  r1.x = (a1.x + b1.x) * linv; r1.y = (a1.y + b1.y) * linv;
  r1.z = (a1.z + b1.z) * linv; r1.w = (a1.w + b1.w) * linv;
  *(float4*)(Out + e)     = r0;
  *(float4*)(Out + e + 4) = r1;
}

extern "C" void kernel_launch(void* const* d_in, const int* in_sizes, int n_in,
                              void* d_out, int out_size, void* d_ws, size_t ws_size,
                              hipStream_t stream) {
  const float* Q = (const float*)d_in[0];
  const float* K = (const float*)d_in[1];
  const float* V = (const float*)d_in[2];
  float* O = (float*)d_out;

  const size_t BHND = (size_t)NBH * NN * DD;   // 4,194,304 floats
  const size_t BHN  = (size_t)NBH * NN;        // 65,536 floats
  const size_t need = (2 * BHND + 2 * BHN) * sizeof(float);  // 34.1 MB

  if (d_ws != nullptr && ws_size >= need) {
    float* Opart = (float*)d_ws;              // [2][BHND]
    float* Lpart = Opart + 2 * BHND;          // [2][BHN]
    attn_kernel<1><<<dim3(NBH * 16 * 2), dim3(256), 0, stream>>>(
        Q, K, V, O, Opart, Lpart);
    combine_kernel<<<dim3((unsigned)(BHND / (256 * 8))), dim3(256), 0, stream>>>(
        Opart, Opart + BHND, Lpart, Lpart + BHN, O);
  } else {
    attn_kernel<0><<<dim3(NBH * 16), dim3(256), 0, stream>>>(
        Q, K, V, O, nullptr, nullptr);
  }
}

// Round 9
// 144.411 us; speedup vs baseline: 1.0383x; 1.0383x over previous
//
#include <hip/hip_runtime.h>
#include <hip/hip_bf16.h>

// ScaledDotProductAttention: B=2,H=16,D=64,N=2048, fp32 in/out.
// Layout per head: Q,K,V are D x N (N contiguous). scores = Q^T K / sqrt(N),
// P = softmax_k, out[q][v] = sum_k P[q][k] V[v][k], out is N x D.
// Max-free softmax (|scores| <~ 1.5, exp-safe).
// Round 12: resubmit of R11 (container infra failure, no measurement; source
// audited race/bounds/barrier-clean). T15 double-pipeline + T5 setprio on the
// verified R10 dataflow. Single kernel, 512 blocks; 3-buffer LDS rotation;
// one barrier per chunk; body = SP(t+1) [QK^T+exp2+pack] overlapped with
// PV(t) [permlane+MFMA, setprio-wrapped] + stage(t+2) + load(t+3).
// In-reg P via pl32+pl16 and ones-MFMA l: HW-verified R5/R7/R8/R10.

typedef __attribute__((ext_vector_type(8))) short short8;   // 8 bf16 (A/B frag)
typedef __attribute__((ext_vector_type(4))) float f32x4;    // 16x16 C/D frag

#define NN 2048
#define DD 64
#define ROWB 144   // LDS row: 64 bf16 (128 B) + 16 B pad

#if __has_builtin(__builtin_amdgcn_exp2f)
#define EXP2(x) __builtin_amdgcn_exp2f(x)
#else
#define EXP2(x) __expf(0.69314718056f * (x))
#endif

__device__ __forceinline__ unsigned pk2(float a, float b) {
  __hip_bfloat162 hh = __float22bfloat162_rn(make_float2(a, b));  // a -> low short
  unsigned u; __builtin_memcpy(&u, &hh, 4); return u;
}
__device__ __forceinline__ short f2bf(float f) {
  union { float f; unsigned u; } x; x.f = f;
  unsigned r = (x.u + 0x7fffu + ((x.u >> 16) & 1u)) >> 16;  // RNE
  return (short)r;
}
// x[32:63] <-> y[0:31]
__device__ __forceinline__ void pl32swap(unsigned &x, unsigned &y) {
  asm("v_permlane32_swap_b32 %0, %1" : "+v"(x), "+v"(y));
}
// x[16:31]<->y[0:15], x[48:63]<->y[32:47]
__device__ __forceinline__ void pl16swap(unsigned &x, unsigned &y) {
  asm("v_permlane16_swap_b32 %0, %1" : "+v"(x), "+v"(y));
}

__global__ __launch_bounds__(256, 2) void attn_kernel(
    const float* __restrict__ Q, const float* __restrict__ K,
    const float* __restrict__ V, float* __restrict__ Out) {
  const int tid  = threadIdx.x;
  const int wave = tid >> 6, lane = tid & 63;
  const int quad = lane >> 4, l16 = lane & 15;

  const int bh   = blockIdx.x >> 4;   // 16 q-blocks per head (128 q rows each)
  const int qblk = blockIdx.x & 15;

  const float* Qh = Q + (size_t)bh * DD * NN;
  const float* Kh = K + (size_t)bh * DD * NN;
  const float* Vh = V + (size_t)bh * DD * NN;
  float*       Oh = Out + (size_t)bh * NN * DD;

  // 3-buffer rotation: chunk c lives in lds[c % 3]; [K|V] planes.
  __shared__ __align__(16) char lds[3][2][64 * ROWB];   // 55296 B
  auto bK = [&](int c) -> char* { return &lds[c % 3][0][0]; };
  auto bV = [&](int c) -> char* { return &lds[c % 3][1][0]; };

  // ---- Q as B-fragments (16x16x32): B[k=quad*8+j][n=l16]; 2 q-tiles/wave ----
  const float qscale = 0.031881407f;  // log2(e)/sqrt(2048)
  const int qb = qblk * 128 + wave * 32;
  short8 bQ[2][2];
#pragma unroll
  for (int qt = 0; qt < 2; ++qt)
#pragma unroll
    for (int hh = 0; hh < 2; ++hh)
#pragma unroll
      for (int j = 0; j < 8; ++j) {
        int d = hh * 32 + quad * 8 + j;
        bQ[qt][hh][j] = f2bf(Qh[(size_t)d * NN + qb + qt * 16 + l16] * qscale);
      }

  // ones B-fragment for l row-sum on the MFMA pipe
  short8 onesB;
#pragma unroll
  for (int j = 0; j < 8; ++j) onesB[j] = (short)0x3F80;  // bf16 1.0

  f32x4 accO[2][4];   // [qt][vt]: row q=quad*4+r, col v=vt*16+l16
  f32x4 accL[2];      // [qt]: reg r holds l[q=qb+qt*16+quad*4+r]
#pragma unroll
  for (int qt = 0; qt < 2; ++qt) {
    accL[qt] = (f32x4){0.f, 0.f, 0.f, 0.f};
#pragma unroll
    for (int vt = 0; vt < 4; ++vt) accO[qt][vt] = (f32x4){0.f, 0.f, 0.f, 0.f};
  }

  // ---- staging: 256 threads stage 64 keys of K and V per chunk ----
  const int ka = tid & 31, kg = tid >> 5;        // K: d-pair (2ka,2ka+1), keys kg*8..+7
  const int vv = tid >> 2, vko = (tid & 3) * 16; // V: row vv, 16 keys
  const float* kbase0 = Kh + (size_t)(2 * ka) * NN + kg * 8;
  const float* kbase1 = kbase0 + NN;
  const float* vbase  = Vh + (size_t)vv * NN + vko;

  float kA[8], kB[8], vA[16];
  auto load_kv = [&](int k0) {
    const float4* p0 = (const float4*)(kbase0 + k0);
    const float4* p1 = (const float4*)(kbase1 + k0);
    float4 a0 = p0[0], a1 = p0[1];
    float4 b0 = p1[0], b1 = p1[1];
    kA[0] = a0.x; kA[1] = a0.y; kA[2] = a0.z; kA[3] = a0.w;
    kA[4] = a1.x; kA[5] = a1.y; kA[6] = a1.z; kA[7] = a1.w;
    kB[0] = b0.x; kB[1] = b0.y; kB[2] = b0.z; kB[3] = b0.w;
    kB[4] = b1.x; kB[5] = b1.y; kB[6] = b1.z; kB[7] = b1.w;
    const float4* pv = (const float4*)(vbase + k0);
    float4 c0 = pv[0], c1 = pv[1], c2 = pv[2], c3 = pv[3];
    vA[0]  = c0.x; vA[1]  = c0.y; vA[2]  = c0.z; vA[3]  = c0.w;
    vA[4]  = c1.x; vA[5]  = c1.y; vA[6]  = c1.z; vA[7]  = c1.w;
    vA[8]  = c2.x; vA[9]  = c2.y; vA[10] = c2.z; vA[11] = c2.w;
    vA[12] = c3.x; vA[13] = c3.y; vA[14] = c3.z; vA[15] = c3.w;
  };
  auto store_kv = [&](char* dK, char* dV) {
#pragma unroll
    for (int j = 0; j < 8; ++j) {
      int k = kg * 8 + j;
      int g = (ka >> 2) ^ ((k >> 1) & 7);
      *(unsigned*)&dK[k * ROWB + g * 16 + (ka & 3) * 4] = pk2(kA[j], kB[j]);
    }
    uint4 w0 = make_uint4(pk2(vA[0], vA[1]),  pk2(vA[2], vA[3]),
                          pk2(vA[4], vA[5]),  pk2(vA[6], vA[7]));
    uint4 w1 = make_uint4(pk2(vA[8], vA[9]),  pk2(vA[10], vA[11]),
                          pk2(vA[12], vA[13]), pk2(vA[14], vA[15]));
    *(uint4*)&dV[vv * ROWB + vko * 2]      = w0;
    *(uint4*)&dV[vv * ROWB + vko * 2 + 16] = w1;
  };

  const int swr = l16 >> 1;   // KT read-side xor swizzle

  // SP: QK^T + exp2 + pack for one 64-key chunk -> u-state (softmax "fill")
  auto SP = [&](const char* cK, unsigned (&up)[2][2][2][2]) {
#pragma unroll
    for (int ks = 0; ks < 2; ++ks)
#pragma unroll
      for (int k2 = 0; k2 < 2; ++k2) {
        const int kt = ks * 2 + k2;
        const char* row = &cK[(kt * 16 + l16) * ROWB];
        short8 aK0 = *(const short8*)&row[(quad ^ swr) * 16];
        short8 aK1 = *(const short8*)&row[((4 + quad) ^ swr) * 16];
#pragma unroll
        for (int qt = 0; qt < 2; ++qt) {
          f32x4 z = (f32x4){0.f, 0.f, 0.f, 0.f};
          f32x4 sT = __builtin_amdgcn_mfma_f32_16x16x32_bf16(aK0, bQ[qt][0], z, 0, 0, 0);
          sT = __builtin_amdgcn_mfma_f32_16x16x32_bf16(aK1, bQ[qt][1], sT, 0, 0, 0);
          up[ks][qt][k2][0] = pk2(EXP2(sT[0]), EXP2(sT[1]));
          up[ks][qt][k2][1] = pk2(EXP2(sT[2]), EXP2(sT[3]));
        }
      }
  };

  // PV: permlane A-frag assembly (softmax "finish") + PV/l MFMA cluster
  auto PV = [&](const char* cV, unsigned (&up)[2][2][2][2]) {
    __builtin_amdgcn_s_setprio(1);
#pragma unroll
    for (int ks = 0; ks < 2; ++ks) {
      short8 aP[2];
#pragma unroll
      for (int qt = 0; qt < 2; ++qt) {
        unsigned c0 = up[ks][qt][0][0], c2 = up[ks][qt][1][0];
        pl32swap(c0, c2); pl16swap(c0, c2);
        unsigned c1 = up[ks][qt][0][1], c3 = up[ks][qt][1][1];
        pl32swap(c1, c3); pl16swap(c1, c3);
        unsigned w[4] = {c0, c1, c2, c3};
        __builtin_memcpy(&aP[qt], w, 16);
        accL[qt] = __builtin_amdgcn_mfma_f32_16x16x32_bf16(aP[qt], onesB, accL[qt], 0, 0, 0);
      }
#pragma unroll
      for (int vt = 0; vt < 4; ++vt) {
        short8 bVf = *(const short8*)&cV[(vt * 16 + l16) * ROWB + ks * 64 + quad * 16];
        accO[0][vt] = __builtin_amdgcn_mfma_f32_16x16x32_bf16(aP[0], bVf, accO[0][vt], 0, 0, 0);
        accO[1][vt] = __builtin_amdgcn_mfma_f32_16x16x32_bf16(aP[1], bVf, accO[1][vt], 0, 0, 0);
      }
    }
    __builtin_amdgcn_s_setprio(0);
  };

  // ---- prologue: stage chunks 0,1; SP(0); prefetch chunk 2 ----
  load_kv(0);
  store_kv(bK(0), bV(0));
  load_kv(64);
  __syncthreads();

  unsigned up[2][2][2][2], un[2][2][2][2];
  SP(bK(0), up);
  store_kv(bK(1), bV(1));   // chunk 1 (disjoint from buf0 being SP-read)
  load_kv(128);             // chunk 2
  __syncthreads();

  // ---- main loop: body handles SP(it+1) || PV(it), stage(it+2), load(it+3)
  // Buffers it, it+1, it+2 are distinct mod 3 -> one barrier per chunk.
  for (int it = 0; it < 31; ++it) {
    SP(bK(it + 1), un);                    // fill: QK^T + exp2 + pack (VALU-heavy)
    PV(bV(it), up);                        // finish+PV of prev (MFMA-heavy, setprio)
    store_kv(bK(it + 2), bV(it + 2));      // stage chunk it+2 (regs from prev load)
    load_kv(((it + 3) & 31) * 64);         // issue loads for chunk it+3 (wrapped)
#pragma unroll
    for (int a = 0; a < 2; ++a)            // up <- un (static indexing, rule #20)
#pragma unroll
      for (int b = 0; b < 2; ++b)
#pragma unroll
        for (int c = 0; c < 2; ++c)
#pragma unroll
          for (int d = 0; d < 2; ++d) up[a][b][c][d] = un[a][b][c][d];
    __syncthreads();
  }

  // ---- tail: PV of last chunk ----
  PV(bV(31), up);

  // ---- epilogue: l is lane-local in accL; normalize and store ----
#pragma unroll
  for (int qt = 0; qt < 2; ++qt)
#pragma unroll
    for (int r = 0; r < 4; ++r) {
      const float inv = 1.0f / accL[qt][r];
      const int q = qb + qt * 16 + quad * 4 + r;
#pragma unroll
      for (int vt = 0; vt < 4; ++vt)
        Oh[(size_t)q * DD + vt * 16 + l16] = accO[qt][vt][r] * inv;
    }
}

extern "C" void kernel_launch(void* const* d_in, const int* in_sizes, int n_in,
                              void* d_out, int out_size, void* d_ws, size_t ws_size,
                              hipStream_t stream) {
  const float* Q = (const float*)d_in[0];
  const float* K = (const float*)d_in[1];
  const float* V = (const float*)d_in[2];
  float* O = (float*)d_out;
  dim3 grid(2 * 16 * (NN / 128));  // 512 blocks, 4 waves, 128 q-rows each
  attn_kernel<<<grid, dim3(256), 0, stream>>>(Q, K, V, O);
}